// Round 4
// baseline (3128.020 us; speedup 1.0000x reference)
//
#include <hip/hip_runtime.h>
#include <math.h>

#define kN 30000
#define kE 240000
#define kG 64
#define kHSZ (1 << 19)
#define kNW 938  // ceil(30000/32)
#define kMB 256
#define kMT 1024
#define kGSZ (kMB * kMT)  // 262144 >= kE
#define kSMALL 8192

typedef unsigned long long ull;

// ---------------- atomic helpers (AGENT scope, coherent point) ----------------
__device__ __forceinline__ int ald(const int* p) {
  return __hip_atomic_load(p, __ATOMIC_RELAXED, __HIP_MEMORY_SCOPE_AGENT);
}
__device__ __forceinline__ unsigned aldu(const unsigned* p) {
  return __hip_atomic_load(p, __ATOMIC_RELAXED, __HIP_MEMORY_SCOPE_AGENT);
}
__device__ __forceinline__ ull aldull(const ull* p) {
  return __hip_atomic_load(p, __ATOMIC_RELAXED, __HIP_MEMORY_SCOPE_AGENT);
}
__device__ __forceinline__ void astu(unsigned* p, unsigned v) {
  __hip_atomic_store(p, v, __ATOMIC_RELAXED, __HIP_MEMORY_SCOPE_AGENT);
}
__device__ __forceinline__ void astull(ull* p, ull v) {
  __hip_atomic_store(p, v, __ATOMIC_RELAXED, __HIP_MEMORY_SCOPE_AGENT);
}
__device__ __forceinline__ void amax64(ull* p, ull v) {
  __hip_atomic_fetch_max(p, v, __ATOMIC_RELAXED, __HIP_MEMORY_SCOPE_AGENT);
}
__device__ __forceinline__ unsigned enc_f(float x) {
  unsigned u = __float_as_uint(x);
  return (u & 0x80000000u) ? ~u : (u | 0x80000000u);
}
__device__ __forceinline__ float dec_f(unsigned u) {
  u = (u & 0x80000000u) ? (u ^ 0x80000000u) : ~u;
  return __uint_as_float(u);
}
// key: (stamp << 50) | enc(score) << 18 | (262143 - e); atomicMax semantics =
// (newest stamp, highest score, lowest edge id) wins.
__device__ __forceinline__ ull mk_key(int r, unsigned enc, int e) {
  return ((ull)r << 50) | ((ull)enc << 18) | (ull)(262143 - e);
}

// fan-out grid barrier for kMB co-resident WGs. arr/go are 64B-strided flag
// arrays. Also broadcasts *cntp (read by WG0 after all arrivals) to every
// block, packed as (count<<14)|gen. Returns the count.
__device__ __forceinline__ int fan_bar(unsigned* arr, unsigned* go, int& gen,
                                       const int* cntp) {
  __shared__ unsigned shv;
  const unsigned g = (unsigned)(++gen);
  __syncthreads();
  const int tid = threadIdx.x;
  if (blockIdx.x == 0) {
    if (tid > 0 && tid < kMB) {
      while (__hip_atomic_load(&arr[tid << 4], __ATOMIC_ACQUIRE,
                               __HIP_MEMORY_SCOPE_AGENT) != g)
        __builtin_amdgcn_s_sleep(4);
    }
    __syncthreads();
    if (tid == 0) {
      unsigned v = 0;
      if (cntp)
        v = (unsigned)__hip_atomic_load(cntp, __ATOMIC_RELAXED,
                                        __HIP_MEMORY_SCOPE_AGENT);
      shv = v;
    }
    __syncthreads();
    unsigned out = (shv << 14) | g;
    if (tid < kMB)
      __hip_atomic_store(&go[tid << 4], out, __ATOMIC_RELEASE,
                         __HIP_MEMORY_SCOPE_AGENT);
    return (int)shv;
  } else {
    if (tid == 0) {
      __hip_atomic_store(&arr[(unsigned)blockIdx.x << 4], g, __ATOMIC_RELEASE,
                         __HIP_MEMORY_SCOPE_AGENT);
      unsigned v;
      while ((((v = __hip_atomic_load(&go[(unsigned)blockIdx.x << 4],
                                      __ATOMIC_ACQUIRE,
                                      __HIP_MEMORY_SCOPE_AGENT))) &
              0x3FFFu) != g)
        __builtin_amdgcn_s_sleep(4);
      shv = v >> 14;
    }
    __syncthreads();
    return (int)shv;
  }
}

// ---------------- embed: z = x @ W_embed ----------------
__global__ __launch_bounds__(256) void k_embed(const float* __restrict__ x,
                                               const float* __restrict__ W,
                                               float* __restrict__ z) {
  __shared__ float sW[128 * 64];  // 32 KB
  int tid = threadIdx.x;
  for (int i = tid; i < 128 * 64; i += 256) sW[i] = W[i];
  __syncthreads();
  int lane = tid & 63, sub = tid >> 6;
  int row0 = blockIdx.x * 16;
  for (int r = sub; r < 16; r += 4) {
    int n = row0 + r;
    if (n >= kN) continue;
    const float* xr = x + (size_t)n * 128;
    float acc = 0.f;
#pragma unroll
    for (int k = 0; k < 128; ++k) acc = fmaf(xr[k], sW[k * 64 + lane], acc);
    z[(size_t)n * 64 + lane] = acc;
  }
}

// ---------------- per-layer init: state + counters (replaces memsets) --------
__global__ void k_init(int* __restrict__ cluster, int* __restrict__ partner,
                       float* __restrict__ mult, int* __restrict__ nmask,
                       unsigned* __restrict__ m_enc, double* __restrict__ den,
                       ull* __restrict__ best, int* __restrict__ meta,
                       int* __restrict__ hkey, int* __restrict__ hmin,
                       float* __restrict__ embs, int layer1) {
  int S = gridDim.x * blockDim.x;
  for (int i = blockIdx.x * blockDim.x + threadIdx.x; i < kHSZ; i += S) {
    if (i < kN) {
      cluster[i] = i;
      partner[i] = -1;
      mult[i] = 1.f;
      if (layer1) nmask[i] = 1;
      m_enc[i] = 0u;
      den[i] = 0.0;
    }
    if (i < 2 * kN) best[i] = 0ULL;  // both parities
    if (i < 32768) meta[i] = 0;      // cnt[16384] + arr[4096] + go[4096] + ctrl
    if (layer1) {
      hkey[i] = -1;
      hmin[i] = 0x7fffffff;
      if (i < 3 * kG * 64) embs[i] = 0.f;
    }
  }
}

// ---------------- per-node half-dots: a[n]=z[n].We_lo, b[n]=z[n].We_hi -------
__global__ __launch_bounds__(1024) void k_ab(const float* __restrict__ z,
                                             const float* __restrict__ We,
                                             int layer, float* __restrict__ a,
                                             float* __restrict__ b) {
  int wid = (blockIdx.x * 1024 + threadIdx.x) >> 6;
  int lane = threadIdx.x & 63;
  int nw = (gridDim.x * 1024) >> 6;
  float wlo = We[layer * 128 + lane];
  float whi = We[layer * 128 + 64 + lane];
  for (int n = wid; n < kN; n += nw) {
    float zv = z[(size_t)n * 64 + lane];
    float fa = zv * wlo, fb = zv * whi;
#pragma unroll
    for (int m = 32; m > 0; m >>= 1) {
      fa += __shfl_xor(fa, m, 64);
      fb += __shfl_xor(fb, m, 64);
    }
    if (lane == 0) {
      a[n] = fa;
      b[n] = fb;
    }
  }
}

// ---------------- raw edge score + segment max (thread per edge) -------------
__global__ void k_rawe(const float* __restrict__ a, const float* __restrict__ b,
                       const float* __restrict__ be, int layer,
                       const int* __restrict__ esrc, const int* __restrict__ edst,
                       const int* __restrict__ emask, float* __restrict__ raws,
                       unsigned* __restrict__ m_enc) {
  int e = blockIdx.x * 256 + threadIdx.x;
  if (e >= kE) return;
  if (emask && !emask[e]) return;
  int t = edst[e];
  float raw = a[esrc[e]] + b[t] + be[layer];
  raws[e] = raw;
  atomicMax(&m_enc[t], enc_f(raw));
}

// ---------------- matching: softmax-finish + locally-dominant contraction ----
// One edge per thread. best is parity-split: stamp x lives in
// best[(x&1)*kN + node]. Single barrier per round: check stamp-r winners
// (parity r&1) and post stamp-(r+1) keys (other parity) in one pass.
__global__ __launch_bounds__(kMT) void k_match_mw(
    const int* __restrict__ esrc, const int* __restrict__ edst,
    const float* __restrict__ raws, const unsigned* __restrict__ m_enc,
    const int* __restrict__ emask, double* __restrict__ den,
    ull* __restrict__ best, unsigned* __restrict__ avail, ull* __restrict__ wl,
    ull* __restrict__ wlB, int* __restrict__ cnt, unsigned* __restrict__ arr,
    unsigned* __restrict__ go, int* __restrict__ ctrl,
    int* __restrict__ cluster, int* __restrict__ partner,
    float* __restrict__ mult, int* __restrict__ nmask) {
  __shared__ unsigned lav[kNW];
  __shared__ int ls;
  const int tid = threadIdx.x;
  const int gtid = blockIdx.x * kMT + tid;
  const int lane = tid & 63;
  int gen = 0;

  // ---- phase 0: avail init + softmax denominator ----
  if (gtid < kNW) {
    unsigned bits = 0u;
    int base = gtid << 5;
    for (int j = 0; j < 32; ++j) {
      int nn = base + j;
      if (nn < kN && nmask[nn]) bits |= (1u << j);
    }
    astu(&avail[gtid], bits);
  }
  const int e = gtid;
  const bool has_e = (e < kE) && (!emask || emask[e]);
  int s = 0, t = 0;
  float raw = 0.f, mx = 0.f;
  if (has_e) {
    s = esrc[e];
    t = edst[e];
    raw = raws[e];
    mx = dec_f(m_enc[t]);
    atomicAdd(&den[t], (double)expf(raw - mx));
  }
  fan_bar(arr, go, gen, nullptr);

  // ---- phase 1: score + post stamp-1 keys (parity 1) ----
  bool alive = false;
  unsigned en = 0;
  if (has_e) {
    if (((aldu(&avail[s >> 5]) >> (s & 31)) & 1u) &&
        ((aldu(&avail[t >> 5]) >> (t & 31)) & 1u)) {
      float ep = expf(raw - mx) / fmaxf((float)den[t], 1e-16f) + 0.5f;
      en = enc_f(ep);
      alive = true;
      ull key = mk_key(1, en, e);
      amax64(&best[kN + s], key);
      if (t != s) amax64(&best[kN + t], key);
    }
  }
  {
    int a = alive ? 1 : 0;
#pragma unroll
    for (int m = 32; m; m >>= 1) a += __shfl_xor(a, m, 64);
    if (lane == 0 && a)
      __hip_atomic_fetch_add(&cnt[0], a, __ATOMIC_RELAXED,
                             __HIP_MEMORY_SCOPE_AGENT);
  }
  int tot = fan_bar(arr, go, gen, &cnt[0]);

  // ---- single-barrier rounds ----
  int r = 1;
  for (; r < 4000; ++r) {
    if (tot == 0) return;
    if (tot < kSMALL) break;  // -> tail
    ull* bchk = best + (size_t)(r & 1) * kN;
    ull* bpost = best + (size_t)((r + 1) & 1) * kN;
    if (alive) {
      if (!((aldu(&avail[s >> 5]) >> (s & 31)) & 1u) ||
          !((aldu(&avail[t >> 5]) >> (t & 31)) & 1u)) {
        alive = false;
      } else {
        ull key = mk_key(r, en, e);
        bool m1 = (aldull(&bchk[s]) == key) && (t == s || aldull(&bchk[t]) == key);
        if (m1) {
          __hip_atomic_fetch_and(&avail[s >> 5], ~(1u << (s & 31)),
                                 __ATOMIC_RELAXED, __HIP_MEMORY_SCOPE_AGENT);
          __hip_atomic_fetch_and(&avail[t >> 5], ~(1u << (t & 31)),
                                 __ATOMIC_RELAXED, __HIP_MEMORY_SCOPE_AGENT);
          cluster[t] = s;
          partner[s] = t;
          mult[s] = dec_f(en);
          if (t != s) nmask[t] = 0;
          alive = false;
        } else {
          ull k2 = mk_key(r + 1, en, e);
          amax64(&bpost[s], k2);
          if (t != s) amax64(&bpost[t], k2);
        }
      }
    }
    int a = alive ? 1 : 0;
#pragma unroll
    for (int m = 32; m; m >>= 1) a += __shfl_xor(a, m, 64);
    if (lane == 0 && a)
      __hip_atomic_fetch_add(&cnt[r], a, __ATOMIC_RELAXED,
                             __HIP_MEMORY_SCOPE_AGENT);
    tot = fan_bar(arr, go, gen, &cnt[r]);
  }

  // ---- handoff: compact survivors into wl (atomic stores -> fabric) ----
  {
    unsigned long long mb = __ballot(alive);
    if (mb) {
      int leader = __ffsll(mb) - 1;
      int base = 0;
      if (lane == leader)
        base = __hip_atomic_fetch_add(&ctrl[0], (int)__popcll(mb),
                                      __ATOMIC_RELAXED, __HIP_MEMORY_SCOPE_AGENT);
      base = __shfl(base, leader, 64);
      if (alive) {
        int idx = base + __popcll(mb & ((1ULL << lane) - 1));
        astull(&wl[2 * idx], ((ull)(unsigned)t << 32) | (unsigned)s);
        astull(&wl[2 * idx + 1], ((ull)(unsigned)e << 32) | en);
      }
    }
  }
  fan_bar(arr, go, gen, nullptr);
  if (blockIdx.x != 0) return;

  // ---- tail: block 0 alone, avail mirrored in LDS ----
  for (int w = tid; w < kNW; w += kMT) lav[w] = aldu(&avail[w]);
  __syncthreads();
  int n = ald(&ctrl[0]);
  ull* cur = wl;
  ull* nxt = wlB;
  for (int rr = r; n > 0 && rr < 60000; ++rr) {
    if (tid == 0) ls = 0;
    __syncthreads();
    ull* bchk = best + (size_t)(rr & 1) * kN;
    ull* bpost = best + (size_t)((rr + 1) & 1) * kN;
    for (int i = tid; i < n; i += kMT) {
      ull lo = aldull(&cur[2 * i]);
      ull hi = aldull(&cur[2 * i + 1]);
      int ss = (int)(unsigned)lo, tt = (int)(lo >> 32);
      unsigned u = (unsigned)hi;
      int ee = (int)(hi >> 32);
      if (!((lav[ss >> 5] >> (ss & 31)) & 1u) ||
          !((lav[tt >> 5] >> (tt & 31)) & 1u))
        continue;
      ull key = mk_key(rr, u, ee);
      bool m1 = (aldull(&bchk[ss]) == key) && (tt == ss || aldull(&bchk[tt]) == key);
      if (m1) {
        atomicAnd(&lav[ss >> 5], ~(1u << (ss & 31)));
        atomicAnd(&lav[tt >> 5], ~(1u << (tt & 31)));
        cluster[tt] = ss;
        partner[ss] = tt;
        mult[ss] = dec_f(u);
        if (tt != ss) nmask[tt] = 0;
      } else {
        ull k2 = mk_key(rr + 1, u, ee);
        amax64(&bpost[ss], k2);
        if (tt != ss) amax64(&bpost[tt], k2);
        int p = atomicAdd(&ls, 1);
        nxt[2 * p] = lo;
        nxt[2 * p + 1] = hi;
      }
    }
    __syncthreads();
    n = ls;
    ull* tmp = cur;
    cur = nxt;
    nxt = tmp;
  }
}

// ---------------- fused merged-features + graph pooling ----------------------
__global__ __launch_bounds__(256) void k_newx_pool(
    const float* __restrict__ z, const int* __restrict__ cluster,
    const int* __restrict__ partner, const float* __restrict__ mult,
    const int* __restrict__ batch, float* __restrict__ zo,
    float* __restrict__ embs_g) {
  int tid = threadIdx.x;
  int d = tid & 63;
  int n0 = blockIdx.x * 128 + (tid >> 6) * 32;
  float acc = 0.f;
  int curg = -1;
  for (int k = 0; k < 32; ++k) {
    int n = n0 + k;
    if (n >= kN) break;
    int g = batch[n];  // wave-uniform load
    if (g != curg) {
      if (curg >= 0 && acc != 0.f) atomicAdd(&embs_g[curg * 64 + d], acc);
      acc = 0.f;
      curg = g;
    }
    float v;
    if (cluster) {
      v = 0.f;
      if (cluster[n] == n) {
        v = z[(size_t)n * 64 + d];
        int p = partner[n];
        if (p >= 0 && p != n) v += z[(size_t)p * 64 + d];
        v *= mult[n];
      }
    } else {
      v = z[(size_t)n * 64 + d];
    }
    if (zo) zo[(size_t)n * 64 + d] = v;
    acc += v;
  }
  if (curg >= 0 && acc != 0.f) atomicAdd(&embs_g[curg * 64 + d], acc);
}

// ---------------- edge remap + hash-dedup (keep min edge id per key) ---------
__global__ void k_remap(const int* __restrict__ esrc, const int* __restrict__ edst,
                        const int* __restrict__ cluster, const int* __restrict__ emask,
                        int* __restrict__ esrcn, int* __restrict__ edstn,
                        int* __restrict__ hkey, int* __restrict__ hmin,
                        int* __restrict__ hslot) {
  int e = blockIdx.x * 256 + threadIdx.x;
  if (e >= kE) return;
  int ns = cluster[esrc[e]];
  int nt = cluster[edst[e]];
  esrcn[e] = ns;
  edstn[e] = nt;
  if (emask && !emask[e]) return;
  int key = ns * kN + nt;  // < 9e8, fits int32
  unsigned h = (((unsigned)key * 2654435761u) >> 13) & (kHSZ - 1);
  while (true) {
    int old = atomicCAS(&hkey[h], -1, key);
    if (old == -1 || old == key) break;
    h = (h + 1) & (kHSZ - 1);
  }
  atomicMin(&hmin[h], e);
  hslot[e] = (int)h;
}

__global__ void k_dedup(const int* __restrict__ emask, const int* __restrict__ hmin,
                        const int* __restrict__ hslot, int* __restrict__ emaskn) {
  int e = blockIdx.x * 256 + threadIdx.x;
  if (e >= kE) return;
  int keep = 0;
  if (!emask || emask[e]) keep = (hmin[hslot[e]] == e) ? 1 : 0;
  emaskn[e] = keep;
}

// ---------------- final FC: out = concat(embs) @ W_fc + b_fc ----------------
__global__ void k_final(const float* __restrict__ embs, const float* __restrict__ Wfc,
                        const float* __restrict__ bfc, float* __restrict__ out) {
  int tid = threadIdx.x;
  if (tid >= kG * 10) return;
  int g = tid / 10, c = tid % 10;
  float acc = bfc[c];
  for (int l = 0; l < 3; ++l)
    for (int d = 0; d < 64; ++d)
      acc += embs[l * (kG * 64) + g * 64 + d] * Wfc[(l * 64 + d) * 10 + c];
  out[g * 10 + c] = acc;
}

extern "C" void kernel_launch(void* const* d_in, const int* in_sizes, int n_in,
                              void* d_out, int out_size, void* d_ws, size_t ws_size,
                              hipStream_t stream) {
  (void)in_sizes; (void)n_in; (void)out_size; (void)ws_size;
  const float* x = (const float*)d_in[0];
  const int* ei = (const int*)d_in[1];  // [2,E]: src = ei, dst = ei + kE
  const int* batch = (const int*)d_in[2];
  const float* Wemb = (const float*)d_in[3];
  const float* We = (const float*)d_in[4];
  const float* be = (const float*)d_in[5];
  const float* Wfc = (const float*)d_in[6];
  const float* bfc = (const float*)d_in[7];
  float* out = (float*)d_out;

  char* ws = (char*)d_ws;
  size_t off = 0;
  auto alloc = [&](size_t bytes) -> void* {
    void* p = ws + off;
    off = (off + bytes + 255) & ~(size_t)255;
    return p;
  };
  float* z0 = (float*)alloc((size_t)kN * 64 * 4);
  float* z1 = (float*)alloc((size_t)kN * 64 * 4);
  float* raws = (float*)alloc((size_t)kE * 4);
  float* an = (float*)alloc((size_t)kN * 4);
  float* bn = (float*)alloc((size_t)kN * 4);
  unsigned* m_enc = (unsigned*)alloc((size_t)kN * 4);
  double* den = (double*)alloc((size_t)kN * 8);
  ull* best = (ull*)alloc((size_t)2 * kN * 8);  // parity-split
  int* cluster = (int*)alloc((size_t)kN * 4);
  int* partner = (int*)alloc((size_t)kN * 4);
  float* mult = (float*)alloc((size_t)kN * 4);
  int* nmask = (int*)alloc((size_t)kN * 4);
  unsigned* avail = (unsigned*)alloc((size_t)kNW * 4);
  int* esrc1 = (int*)alloc((size_t)kE * 4);
  int* edst1 = (int*)alloc((size_t)kE * 4);
  int* emask1 = (int*)alloc((size_t)kE * 4);
  ull* wl = (ull*)alloc((size_t)kSMALL * 16);
  ull* wlB = (ull*)alloc((size_t)kSMALL * 16);
  int* hkey = (int*)alloc((size_t)kHSZ * 4);
  int* hmin = (int*)alloc((size_t)kHSZ * 4);
  int* hslot = (int*)alloc((size_t)kE * 4);
  float* embs = (float*)alloc((size_t)3 * kG * 64 * 4);
  int* meta = (int*)alloc((size_t)32768 * 4);
  int* cnt = meta;                       // [16384]
  unsigned* arr = (unsigned*)(meta + 16384);  // [4096] (256 x 64B)
  unsigned* go = (unsigned*)(meta + 20480);   // [4096]
  int* ctrl = meta + 24576;

  const int gE = (kE + 255) / 256;   // 938
  const int gNP = (kN + 127) / 128;  // 235

  // ---------------- layer 1 ----------------
  k_init<<<512, 256, 0, stream>>>(cluster, partner, mult, nmask, m_enc, den, best,
                                  meta, hkey, hmin, embs, 1);
  k_embed<<<kN / 16, 256, 0, stream>>>(x, Wemb, z0);
  k_newx_pool<<<gNP, 256, 0, stream>>>(z0, nullptr, nullptr, nullptr, batch, nullptr,
                                       embs);  // embs[0]
  k_ab<<<480, 1024, 0, stream>>>(z0, We, 0, an, bn);
  k_rawe<<<gE, 256, 0, stream>>>(an, bn, be, 0, ei, ei + kE, nullptr, raws, m_enc);
  k_match_mw<<<kMB, kMT, 0, stream>>>(ei, ei + kE, raws, m_enc, nullptr, den, best,
                                      avail, wl, wlB, cnt, arr, go, ctrl, cluster,
                                      partner, mult, nmask);
  k_newx_pool<<<gNP, 256, 0, stream>>>(z0, cluster, partner, mult, batch, z1,
                                       embs + kG * 64);  // z1 + embs[1]
  k_remap<<<gE, 256, 0, stream>>>(ei, ei + kE, cluster, nullptr, esrc1, edst1, hkey,
                                  hmin, hslot);
  k_dedup<<<gE, 256, 0, stream>>>(nullptr, hmin, hslot, emask1);

  // ---------------- layer 2 ----------------
  k_init<<<512, 256, 0, stream>>>(cluster, partner, mult, nmask, m_enc, den, best,
                                  meta, hkey, hmin, embs, 0);
  k_ab<<<480, 1024, 0, stream>>>(z1, We, 1, an, bn);
  k_rawe<<<gE, 256, 0, stream>>>(an, bn, be, 1, esrc1, edst1, emask1, raws, m_enc);
  k_match_mw<<<kMB, kMT, 0, stream>>>(esrc1, edst1, raws, m_enc, emask1, den, best,
                                      avail, wl, wlB, cnt, arr, go, ctrl, cluster,
                                      partner, mult, nmask);
  k_newx_pool<<<gNP, 256, 0, stream>>>(z1, cluster, partner, mult, batch, nullptr,
                                       embs + 2 * kG * 64);  // embs[2]

  k_final<<<1, 640, 0, stream>>>(embs, Wfc, bfc, out);
}

// Round 5
// 1274.966 us; speedup vs baseline: 2.4534x; 2.4534x over previous
//
#include <hip/hip_runtime.h>
#include <math.h>

#define kN 30000
#define kE 240000
#define kG 64
#define kHSZ (1 << 19)
#define kNW 938  // ceil(30000/32)
#define kMB 64
#define kMT 1024
#define kGSZ (kMB * kMT)
#define kCAP 4      // ceil(kE / kGSZ)
#define kSMALL 8192

typedef unsigned long long ull;

// ---------------- atomic helpers ----------------
// AGENT scope: cross-WG shared state (device coherent point).
__device__ __forceinline__ int ald(const int* p) {
  return __hip_atomic_load(p, __ATOMIC_RELAXED, __HIP_MEMORY_SCOPE_AGENT);
}
__device__ __forceinline__ unsigned aldu(const unsigned* p) {
  return __hip_atomic_load(p, __ATOMIC_RELAXED, __HIP_MEMORY_SCOPE_AGENT);
}
__device__ __forceinline__ ull aldull(const ull* p) {
  return __hip_atomic_load(p, __ATOMIC_RELAXED, __HIP_MEMORY_SCOPE_AGENT);
}
__device__ __forceinline__ void amax64(ull* p, ull v) {
  __hip_atomic_fetch_max(p, v, __ATOMIC_RELAXED, __HIP_MEMORY_SCOPE_AGENT);
}
// WORKGROUP scope: tail phase, block 0 exclusively owns the state -> local
// L1/L2 latency instead of cross-XCD fabric.
__device__ __forceinline__ ull wldull(const ull* p) {
  return __hip_atomic_load(p, __ATOMIC_RELAXED, __HIP_MEMORY_SCOPE_WORKGROUP);
}
__device__ __forceinline__ void wmax64(ull* p, ull v) {
  __hip_atomic_fetch_max(p, v, __ATOMIC_RELAXED, __HIP_MEMORY_SCOPE_WORKGROUP);
}
__device__ __forceinline__ unsigned enc_f(float x) {
  unsigned u = __float_as_uint(x);
  return (u & 0x80000000u) ? ~u : (u | 0x80000000u);
}
__device__ __forceinline__ float dec_f(unsigned u) {
  u = (u & 0x80000000u) ? (u ^ 0x80000000u) : ~u;
  return __uint_as_float(u);
}
// key: (stamp << 50) | enc(score) << 18 | (262143 - e); atomicMax semantics =
// (newest stamp, highest score, lowest edge id) wins. stamp < 16384.
__device__ __forceinline__ ull mk_key(int r, unsigned enc, int e) {
  return ((ull)r << 50) | ((ull)enc << 18) | (ull)(262143 - e);
}

// centralized grid barrier: 64 co-resident WGs
__device__ __forceinline__ void round_bar(int* bar, int* gen) {
  __syncthreads();
  if (threadIdx.x == 0) {
    int g = ++(*gen);
    __hip_atomic_fetch_add(bar, 1, __ATOMIC_ACQ_REL, __HIP_MEMORY_SCOPE_AGENT);
    while (__hip_atomic_load(bar, __ATOMIC_ACQUIRE, __HIP_MEMORY_SCOPE_AGENT) < kMB * g)
      __builtin_amdgcn_s_sleep(2);
  }
  __syncthreads();
}

// ---------------- embed: z = x @ W_embed ----------------
__global__ __launch_bounds__(256) void k_embed(const float* __restrict__ x,
                                               const float* __restrict__ W,
                                               float* __restrict__ z) {
  __shared__ float sW[128 * 64];  // 32 KB
  int tid = threadIdx.x;
  for (int i = tid; i < 128 * 64; i += 256) sW[i] = W[i];
  __syncthreads();
  int lane = tid & 63, sub = tid >> 6;
  int row0 = blockIdx.x * 16;
  for (int r = sub; r < 16; r += 4) {
    int n = row0 + r;
    if (n >= kN) continue;
    const float* xr = x + (size_t)n * 128;
    float acc = 0.f;
#pragma unroll
    for (int k = 0; k < 128; ++k) acc = fmaf(xr[k], sW[k * 64 + lane], acc);
    z[(size_t)n * 64 + lane] = acc;
  }
}

// ---------------- per-layer init: state + counters (replaces memsets) --------
__global__ void k_init(int* __restrict__ cluster, int* __restrict__ partner,
                       float* __restrict__ mult, int* __restrict__ nmask,
                       unsigned* __restrict__ m_enc, double* __restrict__ den,
                       ull* __restrict__ best, int* __restrict__ cnt,
                       int* __restrict__ ctrl, int* __restrict__ hkey,
                       int* __restrict__ hmin, float* __restrict__ embs,
                       int layer1) {
  int S = gridDim.x * blockDim.x;
  for (int i = blockIdx.x * blockDim.x + threadIdx.x; i < kHSZ; i += S) {
    if (i < kN) {
      cluster[i] = i;
      partner[i] = -1;
      mult[i] = 1.f;
      if (layer1) nmask[i] = 1;
      m_enc[i] = 0u;
      den[i] = 0.0;
    }
    if (i < 2 * kN) best[i] = 0ULL;  // both parities
    if (i < 16384) cnt[i] = 0;
    if (i < 8) ctrl[i] = 0;
    if (layer1) {
      hkey[i] = -1;
      hmin[i] = 0x7fffffff;
      if (i < 3 * kG * 64) embs[i] = 0.f;
    }
  }
}

// ---------------- per-node half-dots: a[n]=z[n].We_lo, b[n]=z[n].We_hi -------
__global__ __launch_bounds__(1024) void k_ab(const float* __restrict__ z,
                                             const float* __restrict__ We,
                                             int layer, float* __restrict__ a,
                                             float* __restrict__ b) {
  int wid = (blockIdx.x * 1024 + threadIdx.x) >> 6;
  int lane = threadIdx.x & 63;
  int nw = (gridDim.x * 1024) >> 6;
  float wlo = We[layer * 128 + lane];
  float whi = We[layer * 128 + 64 + lane];
  for (int n = wid; n < kN; n += nw) {
    float zv = z[(size_t)n * 64 + lane];
    float fa = zv * wlo, fb = zv * whi;
#pragma unroll
    for (int m = 32; m > 0; m >>= 1) {
      fa += __shfl_xor(fa, m, 64);
      fb += __shfl_xor(fb, m, 64);
    }
    if (lane == 0) {
      a[n] = fa;
      b[n] = fb;
    }
  }
}

// ---------------- raw edge score + segment max (thread per edge) -------------
__global__ void k_rawe(const float* __restrict__ a, const float* __restrict__ b,
                       const float* __restrict__ be, int layer,
                       const int* __restrict__ esrc, const int* __restrict__ edst,
                       const int* __restrict__ emask, float* __restrict__ raws,
                       unsigned* __restrict__ m_enc) {
  int e = blockIdx.x * 256 + threadIdx.x;
  if (e >= kE) return;
  if (emask && !emask[e]) return;
  int t = edst[e];
  float raw = a[esrc[e]] + b[t] + be[layer];
  raws[e] = raw;
  atomicMax(&m_enc[t], enc_f(raw));
}

// ---------------- matching: softmax-finish + locally-dominant contraction ----
// best is parity-split: stamp x lives in best[(x&1)*kN + node]. Single barrier
// per round: check stamp-r winners (parity r&1) and post stamp-(r+1) keys
// (parity (r+1)&1) in one pass.
__global__ __launch_bounds__(kMT) void k_match_mw(
    const int* __restrict__ esrc, const int* __restrict__ edst,
    const float* __restrict__ raws, const unsigned* __restrict__ m_enc,
    const int* __restrict__ emask, double* __restrict__ den,
    ull* __restrict__ best, unsigned* __restrict__ avail,
    int4* __restrict__ wl, int4* __restrict__ wlB, int* __restrict__ ctrl,
    int* __restrict__ cnt, int* __restrict__ cluster, int* __restrict__ partner,
    float* __restrict__ mult, int* __restrict__ nmask) {
  const int tid = threadIdx.x;
  const int gtid = blockIdx.x * kMT + tid;
  const int lane = tid & 63;
  int gen = 0;

  // ---- pre-phase: avail init + softmax denominator ----
  for (int w = gtid; w < kNW; w += kGSZ) {
    unsigned bits = 0u;
    int base = w << 5;
    for (int j = 0; j < 32; ++j) {
      int nn = base + j;
      if (nn < kN && nmask[nn]) bits |= (1u << j);
    }
    __hip_atomic_store(&avail[w], bits, __ATOMIC_RELAXED, __HIP_MEMORY_SCOPE_AGENT);
  }
  for (int e = gtid; e < kE; e += kGSZ) {
    if (emask && !emask[e]) continue;
    int t = edst[e];
    float ex = expf(raws[e] - dec_f(m_enc[t]));
    atomicAdd(&den[t], (double)ex);
  }
  round_bar(&ctrl[0], &gen);

  // ---- build register-resident worklist + post stamp-1 keys (parity 1) ----
  int es[kCAP], et[kCAP], ee[kCAP];
  unsigned en[kCAP];
  int myc = 0;
#pragma unroll
  for (int k = 0; k < kCAP; ++k) {
    ee[k] = -1;
    int e = gtid + k * kGSZ;
    if (e >= kE) continue;
    if (emask && !emask[e]) continue;
    int s = esrc[e], t = edst[e];
    if (!((aldu(&avail[s >> 5]) >> (s & 31)) & 1u)) continue;
    if (!((aldu(&avail[t >> 5]) >> (t & 31)) & 1u)) continue;
    float ex = expf(raws[e] - dec_f(m_enc[t]));
    float ep = ex / fmaxf((float)den[t], 1e-16f) + 0.5f;
    unsigned u = enc_f(ep);
    es[k] = s; et[k] = t; en[k] = u; ee[k] = e;
    ++myc;
    ull key = mk_key(1, u, e);
    amax64(&best[kN + s], key);
    if (t != s) amax64(&best[kN + t], key);
  }
  {
    int a = myc;
#pragma unroll
    for (int m = 32; m; m >>= 1) a += __shfl_xor(a, m, 64);
    if (lane == 0 && a)
      __hip_atomic_fetch_add(&cnt[0], a, __ATOMIC_RELAXED, __HIP_MEMORY_SCOPE_AGENT);
  }

  // ---- single-barrier rounds ----
  int r = 1;
  bool to_tail = false;
  for (; r < 8000; ++r) {
    round_bar(&ctrl[0], &gen);
    int tot = ald(&cnt[r - 1]);
    if (tot == 0) return;
    if (tot < kSMALL) { to_tail = true; break; }
    ull* bchk = best + (size_t)(r & 1) * kN;
    ull* bpost = best + (size_t)((r + 1) & 1) * kN;
    int alive = 0;
#pragma unroll
    for (int k = 0; k < kCAP; ++k) {
      if (ee[k] < 0) continue;
      int s = es[k], t = et[k];
      if (!((aldu(&avail[s >> 5]) >> (s & 31)) & 1u) ||
          !((aldu(&avail[t >> 5]) >> (t & 31)) & 1u)) {
        ee[k] = -1;
        continue;
      }
      ull key = mk_key(r, en[k], ee[k]);
      bool m1 = (aldull(&bchk[s]) == key) && (t == s || aldull(&bchk[t]) == key);
      if (m1) {
        __hip_atomic_fetch_and(&avail[s >> 5], ~(1u << (s & 31)), __ATOMIC_RELAXED,
                               __HIP_MEMORY_SCOPE_AGENT);
        __hip_atomic_fetch_and(&avail[t >> 5], ~(1u << (t & 31)), __ATOMIC_RELAXED,
                               __HIP_MEMORY_SCOPE_AGENT);
        cluster[t] = s;
        partner[s] = t;
        mult[s] = dec_f(en[k]);
        if (t != s) nmask[t] = 0;
        ee[k] = -1;
      } else {
        ull k2 = mk_key(r + 1, en[k], ee[k]);
        amax64(&bpost[s], k2);
        if (t != s) amax64(&bpost[t], k2);
        ++alive;
      }
    }
    int a = alive;
#pragma unroll
    for (int m = 32; m; m >>= 1) a += __shfl_xor(a, m, 64);
    if (lane == 0 && a)
      __hip_atomic_fetch_add(&cnt[r], a, __ATOMIC_RELAXED, __HIP_MEMORY_SCOPE_AGENT);
  }
  if (!to_tail) return;

  // ---- handoff: compact surviving entries to global wl ----
#pragma unroll
  for (int k = 0; k < kCAP; ++k) {
    bool act = (ee[k] >= 0);
    unsigned long long mb = __ballot(act);
    if (!mb) continue;
    int leader = __ffsll(mb) - 1;
    int base = 0;
    if (lane == leader)
      base = __hip_atomic_fetch_add(&ctrl[1], (int)__popcll(mb), __ATOMIC_RELAXED,
                                    __HIP_MEMORY_SCOPE_AGENT);
    base = __shfl(base, leader, 64);
    if (act)
      wl[base + __popcll(mb & ((1ULL << lane) - 1))] =
          make_int4(es[k], et[k], (int)en[k], ee[k]);
  }
  round_bar(&ctrl[0], &gen);
  if (blockIdx.x != 0) return;

  // ---- tail: block 0 alone. avail in LDS; best via WORKGROUP-scope atomics
  // (block 0 exclusively owns all tail state -> local cache latency).
  __shared__ unsigned lav[kNW];
  __shared__ int ls;
  for (int w = tid; w < kNW; w += kMT) lav[w] = aldu(&avail[w]);
  __syncthreads();
  int n = ald(&ctrl[1]);
  int4* cur = wl;
  int4* nxt = wlB;
  for (int rr = r; n > 0 && rr < 16300; ++rr) {
    if (tid == 0) ls = 0;
    __syncthreads();
    ull* bchk = best + (size_t)(rr & 1) * kN;
    ull* bpost = best + (size_t)((rr + 1) & 1) * kN;
    for (int i = tid; i < n; i += kMT) {
      int4 E = cur[i];
      int ss = E.x, tt = E.y, e = E.w;
      unsigned u = (unsigned)E.z;
      if (!((lav[ss >> 5] >> (ss & 31)) & 1u) || !((lav[tt >> 5] >> (tt & 31)) & 1u))
        continue;
      ull key = mk_key(rr, u, e);
      bool m1 = (wldull(&bchk[ss]) == key) && (tt == ss || wldull(&bchk[tt]) == key);
      if (m1) {
        atomicAnd(&lav[ss >> 5], ~(1u << (ss & 31)));
        atomicAnd(&lav[tt >> 5], ~(1u << (tt & 31)));
        cluster[tt] = ss;
        partner[ss] = tt;
        mult[ss] = dec_f(u);
        if (tt != ss) nmask[tt] = 0;
      } else {
        ull k2 = mk_key(rr + 1, u, e);
        wmax64(&bpost[ss], k2);
        if (tt != ss) wmax64(&bpost[tt], k2);
        int p = atomicAdd(&ls, 1);
        nxt[p] = E;
      }
    }
    __syncthreads();
    n = ls;
    int4* tmp = cur;
    cur = nxt;
    nxt = tmp;
  }
}

// ---------------- fused merged-features + graph pooling ----------------------
__global__ __launch_bounds__(256) void k_newx_pool(
    const float* __restrict__ z, const int* __restrict__ cluster,
    const int* __restrict__ partner, const float* __restrict__ mult,
    const int* __restrict__ batch, float* __restrict__ zo,
    float* __restrict__ embs_g) {
  int tid = threadIdx.x;
  int d = tid & 63;
  int n0 = blockIdx.x * 128 + (tid >> 6) * 32;
  float acc = 0.f;
  int curg = -1;
  for (int k = 0; k < 32; ++k) {
    int n = n0 + k;
    if (n >= kN) break;
    int g = batch[n];  // wave-uniform load
    if (g != curg) {
      if (curg >= 0 && acc != 0.f) atomicAdd(&embs_g[curg * 64 + d], acc);
      acc = 0.f;
      curg = g;
    }
    float v;
    if (cluster) {
      v = 0.f;
      if (cluster[n] == n) {
        v = z[(size_t)n * 64 + d];
        int p = partner[n];
        if (p >= 0 && p != n) v += z[(size_t)p * 64 + d];
        v *= mult[n];
      }
    } else {
      v = z[(size_t)n * 64 + d];
    }
    if (zo) zo[(size_t)n * 64 + d] = v;
    acc += v;
  }
  if (curg >= 0 && acc != 0.f) atomicAdd(&embs_g[curg * 64 + d], acc);
}

// ---------------- edge remap + hash-dedup (keep min edge id per key) ---------
__global__ void k_remap(const int* __restrict__ esrc, const int* __restrict__ edst,
                        const int* __restrict__ cluster, const int* __restrict__ emask,
                        int* __restrict__ esrcn, int* __restrict__ edstn,
                        int* __restrict__ hkey, int* __restrict__ hmin,
                        int* __restrict__ hslot) {
  int e = blockIdx.x * 256 + threadIdx.x;
  if (e >= kE) return;
  int ns = cluster[esrc[e]];
  int nt = cluster[edst[e]];
  esrcn[e] = ns;
  edstn[e] = nt;
  if (emask && !emask[e]) return;
  int key = ns * kN + nt;  // < 9e8, fits int32
  unsigned h = (((unsigned)key * 2654435761u) >> 13) & (kHSZ - 1);
  while (true) {
    int old = atomicCAS(&hkey[h], -1, key);
    if (old == -1 || old == key) break;
    h = (h + 1) & (kHSZ - 1);
  }
  atomicMin(&hmin[h], e);
  hslot[e] = (int)h;
}

__global__ void k_dedup(const int* __restrict__ emask, const int* __restrict__ hmin,
                        const int* __restrict__ hslot, int* __restrict__ emaskn) {
  int e = blockIdx.x * 256 + threadIdx.x;
  if (e >= kE) return;
  int keep = 0;
  if (!emask || emask[e]) keep = (hmin[hslot[e]] == e) ? 1 : 0;
  emaskn[e] = keep;
}

// ---------------- final FC: out = concat(embs) @ W_fc + b_fc ----------------
__global__ void k_final(const float* __restrict__ embs, const float* __restrict__ Wfc,
                        const float* __restrict__ bfc, float* __restrict__ out) {
  int tid = threadIdx.x;
  if (tid >= kG * 10) return;
  int g = tid / 10, c = tid % 10;
  float acc = bfc[c];
  for (int l = 0; l < 3; ++l)
    for (int d = 0; d < 64; ++d)
      acc += embs[l * (kG * 64) + g * 64 + d] * Wfc[(l * 64 + d) * 10 + c];
  out[g * 10 + c] = acc;
}

extern "C" void kernel_launch(void* const* d_in, const int* in_sizes, int n_in,
                              void* d_out, int out_size, void* d_ws, size_t ws_size,
                              hipStream_t stream) {
  (void)in_sizes; (void)n_in; (void)out_size; (void)ws_size;
  const float* x = (const float*)d_in[0];
  const int* ei = (const int*)d_in[1];  // [2,E]: src = ei, dst = ei + kE
  const int* batch = (const int*)d_in[2];
  const float* Wemb = (const float*)d_in[3];
  const float* We = (const float*)d_in[4];
  const float* be = (const float*)d_in[5];
  const float* Wfc = (const float*)d_in[6];
  const float* bfc = (const float*)d_in[7];
  float* out = (float*)d_out;

  char* ws = (char*)d_ws;
  size_t off = 0;
  auto alloc = [&](size_t bytes) -> void* {
    void* p = ws + off;
    off = (off + bytes + 255) & ~(size_t)255;
    return p;
  };
  float* z0 = (float*)alloc((size_t)kN * 64 * 4);
  float* z1 = (float*)alloc((size_t)kN * 64 * 4);
  float* raws = (float*)alloc((size_t)kE * 4);
  float* an = (float*)alloc((size_t)kN * 4);
  float* bn = (float*)alloc((size_t)kN * 4);
  unsigned* m_enc = (unsigned*)alloc((size_t)kN * 4);
  double* den = (double*)alloc((size_t)kN * 8);
  ull* best = (ull*)alloc((size_t)2 * kN * 8);  // parity-split
  int* cluster = (int*)alloc((size_t)kN * 4);
  int* partner = (int*)alloc((size_t)kN * 4);
  float* mult = (float*)alloc((size_t)kN * 4);
  int* nmask = (int*)alloc((size_t)kN * 4);
  unsigned* avail = (unsigned*)alloc((size_t)kNW * 4);
  int* esrc1 = (int*)alloc((size_t)kE * 4);
  int* edst1 = (int*)alloc((size_t)kE * 4);
  int* emask1 = (int*)alloc((size_t)kE * 4);
  int4* wl = (int4*)alloc((size_t)kE * 16);
  int4* wlB = (int4*)alloc((size_t)kE * 16);
  int* hkey = (int*)alloc((size_t)kHSZ * 4);
  int* hmin = (int*)alloc((size_t)kHSZ * 4);
  int* hslot = (int*)alloc((size_t)kE * 4);
  float* embs = (float*)alloc((size_t)3 * kG * 64 * 4);
  int* cnt = (int*)alloc((size_t)16384 * 4);
  int* ctrl = (int*)alloc(256);

  const int gE = (kE + 255) / 256;   // 938
  const int gNP = (kN + 127) / 128;  // 235

  // ---------------- layer 1 ----------------
  k_init<<<512, 256, 0, stream>>>(cluster, partner, mult, nmask, m_enc, den, best,
                                  cnt, ctrl, hkey, hmin, embs, 1);
  k_embed<<<kN / 16, 256, 0, stream>>>(x, Wemb, z0);
  k_newx_pool<<<gNP, 256, 0, stream>>>(z0, nullptr, nullptr, nullptr, batch, nullptr,
                                       embs);  // embs[0]
  k_ab<<<480, 1024, 0, stream>>>(z0, We, 0, an, bn);
  k_rawe<<<gE, 256, 0, stream>>>(an, bn, be, 0, ei, ei + kE, nullptr, raws, m_enc);
  k_match_mw<<<kMB, kMT, 0, stream>>>(ei, ei + kE, raws, m_enc, nullptr, den, best,
                                      avail, wl, wlB, ctrl, cnt, cluster, partner,
                                      mult, nmask);
  k_newx_pool<<<gNP, 256, 0, stream>>>(z0, cluster, partner, mult, batch, z1,
                                       embs + kG * 64);  // z1 + embs[1]
  k_remap<<<gE, 256, 0, stream>>>(ei, ei + kE, cluster, nullptr, esrc1, edst1, hkey,
                                  hmin, hslot);
  k_dedup<<<gE, 256, 0, stream>>>(nullptr, hmin, hslot, emask1);

  // ---------------- layer 2 ----------------
  k_init<<<512, 256, 0, stream>>>(cluster, partner, mult, nmask, m_enc, den, best,
                                  cnt, ctrl, hkey, hmin, embs, 0);
  k_ab<<<480, 1024, 0, stream>>>(z1, We, 1, an, bn);
  k_rawe<<<gE, 256, 0, stream>>>(an, bn, be, 1, esrc1, edst1, emask1, raws, m_enc);
  k_match_mw<<<kMB, kMT, 0, stream>>>(esrc1, edst1, raws, m_enc, emask1, den, best,
                                      avail, wl, wlB, ctrl, cnt, cluster, partner,
                                      mult, nmask);
  k_newx_pool<<<gNP, 256, 0, stream>>>(z1, cluster, partner, mult, batch, nullptr,
                                       embs + 2 * kG * 64);  // embs[2]

  k_final<<<1, 640, 0, stream>>>(embs, Wfc, bfc, out);
}

// Round 6
// 1084.979 us; speedup vs baseline: 2.8830x; 1.1751x over previous
//
#include <hip/hip_runtime.h>
#include <math.h>

#define kN 30000
#define kE 240000
#define kG 64
#define kHSZ (1 << 19)
#define kMB 64
#define kMT 1024
#define kGSZ (kMB * kMT)
#define kCAP 4      // ceil(kE / kGSZ)
#define kSMALL 8192

typedef unsigned long long ull;
#define kDEAD (~0ULL)

// ---------------- atomic helpers ----------------
// AGENT scope: cross-WG shared state (device coherent point).
__device__ __forceinline__ int ald(const int* p) {
  return __hip_atomic_load(p, __ATOMIC_RELAXED, __HIP_MEMORY_SCOPE_AGENT);
}
__device__ __forceinline__ ull aldull(const ull* p) {
  return __hip_atomic_load(p, __ATOMIC_RELAXED, __HIP_MEMORY_SCOPE_AGENT);
}
__device__ __forceinline__ void astull(ull* p, ull v) {
  __hip_atomic_store(p, v, __ATOMIC_RELAXED, __HIP_MEMORY_SCOPE_AGENT);
}
__device__ __forceinline__ void amax64(ull* p, ull v) {
  __hip_atomic_fetch_max(p, v, __ATOMIC_RELAXED, __HIP_MEMORY_SCOPE_AGENT);
}
// WORKGROUP scope: tail phase, block 0 exclusively owns the state.
__device__ __forceinline__ ull wldull(const ull* p) {
  return __hip_atomic_load(p, __ATOMIC_RELAXED, __HIP_MEMORY_SCOPE_WORKGROUP);
}
__device__ __forceinline__ void wstull(ull* p, ull v) {
  __hip_atomic_store(p, v, __ATOMIC_RELAXED, __HIP_MEMORY_SCOPE_WORKGROUP);
}
__device__ __forceinline__ void wmax64(ull* p, ull v) {
  __hip_atomic_fetch_max(p, v, __ATOMIC_RELAXED, __HIP_MEMORY_SCOPE_WORKGROUP);
}
__device__ __forceinline__ unsigned enc_f(float x) {
  unsigned u = __float_as_uint(x);
  return (u & 0x80000000u) ? ~u : (u | 0x80000000u);
}
__device__ __forceinline__ float dec_f(unsigned u) {
  u = (u & 0x80000000u) ? (u ^ 0x80000000u) : ~u;
  return __uint_as_float(u);
}
// key: (stamp << 50) | enc(score) << 18 | (262143 - e); atomicMax semantics =
// (newest stamp, highest score, lowest edge id) wins. stamp < 16383, so
// kDEAD (all ones) is unreachable and absorbing.
__device__ __forceinline__ ull mk_key(int r, unsigned enc, int e) {
  return ((ull)r << 50) | ((ull)enc << 18) | (ull)(262143 - e);
}

// centralized grid barrier: 64 co-resident WGs
__device__ __forceinline__ void round_bar(int* bar, int* gen) {
  __syncthreads();
  if (threadIdx.x == 0) {
    int g = ++(*gen);
    __hip_atomic_fetch_add(bar, 1, __ATOMIC_ACQ_REL, __HIP_MEMORY_SCOPE_AGENT);
    while (__hip_atomic_load(bar, __ATOMIC_ACQUIRE, __HIP_MEMORY_SCOPE_AGENT) < kMB * g)
      __builtin_amdgcn_s_sleep(2);
  }
  __syncthreads();
}

// ---------------- embed: z = x @ W_embed ----------------
__global__ __launch_bounds__(256) void k_embed(const float* __restrict__ x,
                                               const float* __restrict__ W,
                                               float* __restrict__ z) {
  __shared__ float sW[128 * 64];  // 32 KB
  int tid = threadIdx.x;
  for (int i = tid; i < 128 * 64; i += 256) sW[i] = W[i];
  __syncthreads();
  int lane = tid & 63, sub = tid >> 6;
  int row0 = blockIdx.x * 16;
  for (int r = sub; r < 16; r += 4) {
    int n = row0 + r;
    if (n >= kN) continue;
    const float* xr = x + (size_t)n * 128;
    float acc = 0.f;
#pragma unroll
    for (int k = 0; k < 128; ++k) acc = fmaf(xr[k], sW[k * 64 + lane], acc);
    z[(size_t)n * 64 + lane] = acc;
  }
}

// ---------------- per-layer init ----------------
__global__ void k_init(int* __restrict__ cluster, int* __restrict__ partner,
                       float* __restrict__ mult, double* __restrict__ den,
                       ull* __restrict__ best, int* __restrict__ cnt,
                       int* __restrict__ ctrl, int* __restrict__ hkey,
                       int* __restrict__ hmin, float* __restrict__ embs,
                       int layer1) {
  int S = gridDim.x * blockDim.x;
  for (int i = blockIdx.x * blockDim.x + threadIdx.x; i < kHSZ; i += S) {
    if (i < kN) {
      cluster[i] = i;
      partner[i] = -1;
      mult[i] = 1.f;
      den[i] = 0.0;
    }
    if (i < 2 * kN) best[i] = 0ULL;  // both parities
    if (i < 16384) cnt[i] = 0;
    if (i < 8) ctrl[i] = 0;
    if (layer1) {
      hkey[i] = -1;
      hmin[i] = 0x7fffffff;
      if (i < 3 * kG * 64) embs[i] = 0.f;
    }
  }
}

// ---------------- per-node half-dots: a[n]=z[n].We_lo, b[n]=z[n].We_hi -------
__global__ __launch_bounds__(1024) void k_ab(const float* __restrict__ z,
                                             const float* __restrict__ We,
                                             int layer, float* __restrict__ a,
                                             float* __restrict__ b) {
  int wid = (blockIdx.x * 1024 + threadIdx.x) >> 6;
  int lane = threadIdx.x & 63;
  int nw = (gridDim.x * 1024) >> 6;
  float wlo = We[layer * 128 + lane];
  float whi = We[layer * 128 + 64 + lane];
  for (int n = wid; n < kN; n += nw) {
    float zv = z[(size_t)n * 64 + lane];
    float fa = zv * wlo, fb = zv * whi;
#pragma unroll
    for (int m = 32; m > 0; m >>= 1) {
      fa += __shfl_xor(fa, m, 64);
      fb += __shfl_xor(fb, m, 64);
    }
    if (lane == 0) {
      a[n] = fa;
      b[n] = fb;
    }
  }
}

// ---------------- raw edge score + f64 denominator (no-max softmax) ----------
__global__ void k_rawe(const float* __restrict__ a, const float* __restrict__ b,
                       const float* __restrict__ be, int layer,
                       const int* __restrict__ esrc, const int* __restrict__ edst,
                       const int* __restrict__ emask, float* __restrict__ raws,
                       double* __restrict__ den) {
  int e = blockIdx.x * 256 + threadIdx.x;
  if (e >= kE) return;
  if (emask && !emask[e]) return;
  int t = edst[e];
  float raw = a[esrc[e]] + b[t] + be[layer];
  raws[e] = raw;
  atomicAdd(&den[t], exp((double)raw));  // |raw| << 709: no overflow
}

// ---------------- matching: locally-dominant contraction ---------------------
// best is parity-split: stamp x lives in best[(x&1)*kN + node]; kDEAD marks a
// matched (dead) node in both parities. Single barrier per round.
__global__ __launch_bounds__(kMT) void k_match_mw(
    const int* __restrict__ esrc, const int* __restrict__ edst,
    const float* __restrict__ raws, const int* __restrict__ emask,
    const double* __restrict__ den, ull* __restrict__ best,
    int4* __restrict__ wl, int4* __restrict__ wlB, int* __restrict__ ctrl,
    int* __restrict__ cnt, int* __restrict__ cluster, int* __restrict__ partner,
    float* __restrict__ mult) {
  const int tid = threadIdx.x;
  const int gtid = blockIdx.x * kMT + tid;
  const int lane = tid & 63;
  int gen = 0;

  // ---- phase 1: score + post stamp-1 keys (parity 1), pruned by stale reads
  int es[kCAP], et[kCAP], ee[kCAP];
  unsigned en[kCAP];
  int myc = 0;
#pragma unroll
  for (int k = 0; k < kCAP; ++k) {
    ee[k] = -1;
    int e = gtid + k * kGSZ;
    if (e >= kE) continue;
    if (emask && !emask[e]) continue;
    int s = esrc[e], t = edst[e];
    double ex = exp((double)raws[e]);
    float ep = (float)(ex / den[t]) + 0.5f;
    unsigned u = enc_f(ep);
    es[k] = s; et[k] = t; en[k] = u; ee[k] = e;
    ++myc;
    ull key = mk_key(1, u, e);
    // stale cached read is a lower bound of the live max -> safe prune
    if (key > best[kN + s]) amax64(&best[kN + s], key);
    if (t != s && key > best[kN + t]) amax64(&best[kN + t], key);
  }
  {
    int a = myc;
#pragma unroll
    for (int m = 32; m; m >>= 1) a += __shfl_xor(a, m, 64);
    if (lane == 0 && a)
      __hip_atomic_fetch_add(&cnt[0], a, __ATOMIC_RELAXED, __HIP_MEMORY_SCOPE_AGENT);
  }

  // ---- single-barrier rounds ----
  int r = 1;
  bool to_tail = false;
  for (; r < 8000; ++r) {
    round_bar(&ctrl[0], &gen);
    int tot = ald(&cnt[r - 1]);
    if (tot == 0) return;
    if (tot < kSMALL) { to_tail = true; break; }
    ull* bchk = best + (size_t)(r & 1) * kN;
    ull* bpost = best + (size_t)((r + 1) & 1) * kN;
    int alive = 0;
#pragma unroll
    for (int k = 0; k < kCAP; ++k) {
      if (ee[k] < 0) continue;
      int s = es[k], t = et[k];
      ull bs = aldull(&bchk[s]);
      ull bt = (t == s) ? bs : aldull(&bchk[t]);
      if (bs == kDEAD || bt == kDEAD) { ee[k] = -1; continue; }
      ull key = mk_key(r, en[k], ee[k]);
      if (bs == key && bt == key) {
        astull(&bchk[s], kDEAD);
        astull(&bpost[s], kDEAD);
        if (t != s) { astull(&bchk[t], kDEAD); astull(&bpost[t], kDEAD); }
        cluster[t] = s;
        partner[s] = t;
        mult[s] = dec_f(en[k]);
        ee[k] = -1;
      } else {
        ull k2 = mk_key(r + 1, en[k], ee[k]);
        amax64(&bpost[s], k2);
        if (t != s) amax64(&bpost[t], k2);
        ++alive;
      }
    }
    int a = alive;
#pragma unroll
    for (int m = 32; m; m >>= 1) a += __shfl_xor(a, m, 64);
    if (lane == 0 && a)
      __hip_atomic_fetch_add(&cnt[r], a, __ATOMIC_RELAXED, __HIP_MEMORY_SCOPE_AGENT);
  }
  if (!to_tail) return;

  // ---- handoff: compact surviving entries to global wl ----
#pragma unroll
  for (int k = 0; k < kCAP; ++k) {
    bool act = (ee[k] >= 0);
    unsigned long long mb = __ballot(act);
    if (!mb) continue;
    int leader = __ffsll(mb) - 1;
    int base = 0;
    if (lane == leader)
      base = __hip_atomic_fetch_add(&ctrl[1], (int)__popcll(mb), __ATOMIC_RELAXED,
                                    __HIP_MEMORY_SCOPE_AGENT);
    base = __shfl(base, leader, 64);
    if (act)
      wl[base + __popcll(mb & ((1ULL << lane) - 1))] =
          make_int4(es[k], et[k], (int)en[k], ee[k]);
  }
  round_bar(&ctrl[0], &gen);  // AGENT acquire: invalidates L1/L2 for block 0
  if (blockIdx.x != 0) return;

  // ---- tail: block 0 alone, WORKGROUP-scope ops (exclusive owner) ----
  __shared__ int ls;
  int n = ald(&ctrl[1]);
  int4* cur = wl;
  int4* nxt = wlB;
  for (int rr = r; n > 0 && rr < 16300; ++rr) {
    if (tid == 0) ls = 0;
    __syncthreads();
    ull* bchk = best + (size_t)(rr & 1) * kN;
    ull* bpost = best + (size_t)((rr + 1) & 1) * kN;
    for (int i = tid; i < n; i += kMT) {
      int4 E = cur[i];
      int ss = E.x, tt = E.y, e = E.w;
      unsigned u = (unsigned)E.z;
      ull bs = wldull(&bchk[ss]);
      ull bt = (tt == ss) ? bs : wldull(&bchk[tt]);
      if (bs == kDEAD || bt == kDEAD) continue;  // drop
      ull key = mk_key(rr, u, e);
      if (bs == key && bt == key) {
        wstull(&bchk[ss], kDEAD);
        wstull(&bpost[ss], kDEAD);
        if (tt != ss) { wstull(&bchk[tt], kDEAD); wstull(&bpost[tt], kDEAD); }
        cluster[tt] = ss;
        partner[ss] = tt;
        mult[ss] = dec_f(u);
      } else {
        ull k2 = mk_key(rr + 1, u, e);
        wmax64(&bpost[ss], k2);
        if (tt != ss) wmax64(&bpost[tt], k2);
        int p = atomicAdd(&ls, 1);
        nxt[p] = E;
      }
    }
    __syncthreads();
    n = ls;
    int4* tmp = cur;
    cur = nxt;
    nxt = tmp;
  }
}

// ---------------- fused merged-features + graph pooling ----------------------
__global__ __launch_bounds__(256) void k_newx_pool(
    const float* __restrict__ z, const int* __restrict__ cluster,
    const int* __restrict__ partner, const float* __restrict__ mult,
    const int* __restrict__ batch, float* __restrict__ zo,
    float* __restrict__ embs_g) {
  int tid = threadIdx.x;
  int d = tid & 63;
  int n0 = blockIdx.x * 128 + (tid >> 6) * 32;
  float acc = 0.f;
  int curg = -1;
  for (int k = 0; k < 32; ++k) {
    int n = n0 + k;
    if (n >= kN) break;
    int g = batch[n];  // wave-uniform load
    if (g != curg) {
      if (curg >= 0 && acc != 0.f) atomicAdd(&embs_g[curg * 64 + d], acc);
      acc = 0.f;
      curg = g;
    }
    float v;
    if (cluster) {
      v = 0.f;
      if (cluster[n] == n) {
        v = z[(size_t)n * 64 + d];
        int p = partner[n];
        if (p >= 0 && p != n) v += z[(size_t)p * 64 + d];
        v *= mult[n];
      }
    } else {
      v = z[(size_t)n * 64 + d];
    }
    if (zo) zo[(size_t)n * 64 + d] = v;
    acc += v;
  }
  if (curg >= 0 && acc != 0.f) atomicAdd(&embs_g[curg * 64 + d], acc);
}

// ---------------- edge remap + hash-dedup (keep min edge id per key) ---------
__global__ void k_remap(const int* __restrict__ esrc, const int* __restrict__ edst,
                        const int* __restrict__ cluster, const int* __restrict__ emask,
                        int* __restrict__ esrcn, int* __restrict__ edstn,
                        int* __restrict__ hkey, int* __restrict__ hmin,
                        int* __restrict__ hslot) {
  int e = blockIdx.x * 256 + threadIdx.x;
  if (e >= kE) return;
  int ns = cluster[esrc[e]];
  int nt = cluster[edst[e]];
  esrcn[e] = ns;
  edstn[e] = nt;
  if (emask && !emask[e]) return;
  int key = ns * kN + nt;  // < 9e8, fits int32
  unsigned h = (((unsigned)key * 2654435761u) >> 13) & (kHSZ - 1);
  while (true) {
    int old = atomicCAS(&hkey[h], -1, key);
    if (old == -1 || old == key) break;
    h = (h + 1) & (kHSZ - 1);
  }
  atomicMin(&hmin[h], e);
  hslot[e] = (int)h;
}

__global__ void k_dedup(const int* __restrict__ emask, const int* __restrict__ hmin,
                        const int* __restrict__ hslot, int* __restrict__ emaskn) {
  int e = blockIdx.x * 256 + threadIdx.x;
  if (e >= kE) return;
  int keep = 0;
  if (!emask || emask[e]) keep = (hmin[hslot[e]] == e) ? 1 : 0;
  emaskn[e] = keep;
}

// ---------------- final FC: out = concat(embs) @ W_fc + b_fc ----------------
__global__ void k_final(const float* __restrict__ embs, const float* __restrict__ Wfc,
                        const float* __restrict__ bfc, float* __restrict__ out) {
  int tid = threadIdx.x;
  if (tid >= kG * 10) return;
  int g = tid / 10, c = tid % 10;
  float acc = bfc[c];
  for (int l = 0; l < 3; ++l)
    for (int d = 0; d < 64; ++d)
      acc += embs[l * (kG * 64) + g * 64 + d] * Wfc[(l * 64 + d) * 10 + c];
  out[g * 10 + c] = acc;
}

extern "C" void kernel_launch(void* const* d_in, const int* in_sizes, int n_in,
                              void* d_out, int out_size, void* d_ws, size_t ws_size,
                              hipStream_t stream) {
  (void)in_sizes; (void)n_in; (void)out_size; (void)ws_size;
  const float* x = (const float*)d_in[0];
  const int* ei = (const int*)d_in[1];  // [2,E]: src = ei, dst = ei + kE
  const int* batch = (const int*)d_in[2];
  const float* Wemb = (const float*)d_in[3];
  const float* We = (const float*)d_in[4];
  const float* be = (const float*)d_in[5];
  const float* Wfc = (const float*)d_in[6];
  const float* bfc = (const float*)d_in[7];
  float* out = (float*)d_out;

  char* ws = (char*)d_ws;
  size_t off = 0;
  auto alloc = [&](size_t bytes) -> void* {
    void* p = ws + off;
    off = (off + bytes + 255) & ~(size_t)255;
    return p;
  };
  float* z0 = (float*)alloc((size_t)kN * 64 * 4);
  float* z1 = (float*)alloc((size_t)kN * 64 * 4);
  float* raws = (float*)alloc((size_t)kE * 4);
  float* an = (float*)alloc((size_t)kN * 4);
  float* bn = (float*)alloc((size_t)kN * 4);
  double* den = (double*)alloc((size_t)kN * 8);
  ull* best = (ull*)alloc((size_t)2 * kN * 8);  // parity-split
  int* cluster = (int*)alloc((size_t)kN * 4);
  int* partner = (int*)alloc((size_t)kN * 4);
  float* mult = (float*)alloc((size_t)kN * 4);
  int* esrc1 = (int*)alloc((size_t)kE * 4);
  int* edst1 = (int*)alloc((size_t)kE * 4);
  int* emask1 = (int*)alloc((size_t)kE * 4);
  int4* wl = (int4*)alloc((size_t)kSMALL * 16);
  int4* wlB = (int4*)alloc((size_t)kSMALL * 16);
  int* hkey = (int*)alloc((size_t)kHSZ * 4);
  int* hmin = (int*)alloc((size_t)kHSZ * 4);
  int* hslot = (int*)alloc((size_t)kE * 4);
  float* embs = (float*)alloc((size_t)3 * kG * 64 * 4);
  int* cnt = (int*)alloc((size_t)16384 * 4);
  int* ctrl = (int*)alloc(256);

  const int gE = (kE + 255) / 256;   // 938
  const int gNP = (kN + 127) / 128;  // 235

  // ---------------- layer 1 ----------------
  k_init<<<512, 256, 0, stream>>>(cluster, partner, mult, den, best, cnt, ctrl,
                                  hkey, hmin, embs, 1);
  k_embed<<<kN / 16, 256, 0, stream>>>(x, Wemb, z0);
  k_newx_pool<<<gNP, 256, 0, stream>>>(z0, nullptr, nullptr, nullptr, batch, nullptr,
                                       embs);  // embs[0]
  k_ab<<<480, 1024, 0, stream>>>(z0, We, 0, an, bn);
  k_rawe<<<gE, 256, 0, stream>>>(an, bn, be, 0, ei, ei + kE, nullptr, raws, den);
  k_match_mw<<<kMB, kMT, 0, stream>>>(ei, ei + kE, raws, nullptr, den, best, wl, wlB,
                                      ctrl, cnt, cluster, partner, mult);
  k_newx_pool<<<gNP, 256, 0, stream>>>(z0, cluster, partner, mult, batch, z1,
                                       embs + kG * 64);  // z1 + embs[1]
  k_remap<<<gE, 256, 0, stream>>>(ei, ei + kE, cluster, nullptr, esrc1, edst1, hkey,
                                  hmin, hslot);
  k_dedup<<<gE, 256, 0, stream>>>(nullptr, hmin, hslot, emask1);

  // ---------------- layer 2 ----------------
  k_init<<<512, 256, 0, stream>>>(cluster, partner, mult, den, best, cnt, ctrl,
                                  hkey, hmin, embs, 0);
  k_ab<<<480, 1024, 0, stream>>>(z1, We, 1, an, bn);
  k_rawe<<<gE, 256, 0, stream>>>(an, bn, be, 1, esrc1, edst1, emask1, raws, den);
  k_match_mw<<<kMB, kMT, 0, stream>>>(esrc1, edst1, raws, emask1, den, best, wl, wlB,
                                      ctrl, cnt, cluster, partner, mult);
  k_newx_pool<<<gNP, 256, 0, stream>>>(z1, cluster, partner, mult, batch, nullptr,
                                       embs + 2 * kG * 64);  // embs[2]

  k_final<<<1, 640, 0, stream>>>(embs, Wfc, bfc, out);
}